// Round 2
// baseline (349.330 us; speedup 1.0000x reference)
//
#include <hip/hip_runtime.h>
#include <hip/hip_cooperative_groups.h>
#include <hip/hip_bf16.h>
#include <cstdint>

namespace cg = cooperative_groups;

// Problem constants (reference: BATCH=4096, N_VIEWS=2, T=0.07, D=128 -> N=8192)
#define NROWS 8192
#define FDIM  128
#define HALF_N 4096

typedef short bf16x8 __attribute__((ext_vector_type(8)));   // 8 bf16 = 4 VGPRs
typedef float f32x4  __attribute__((ext_vector_type(4)));

// k1 = log2(e)/T so exp((s-1)/T) = exp2(k1*s - k1)
#define K1 (1.4426950408889634f / 0.07f)

#if __has_builtin(__builtin_amdgcn_exp2f)
#define EXP2(x) __builtin_amdgcn_exp2f(x)       // raw v_exp_f32
#else
#define EXP2(x) exp2f(x)
#endif

// Upper-triangle block count at (128-row x 256-col) granularity:
// per col-group J (0..31), rb = 0..2J+1 kept -> sum(2J+2) = 32*33 = 1056.
#define NBLK_TRI 1056
#define NBLK_ALL (NBLK_TRI + 32)     // + pos/diag blocks

__device__ __forceinline__ float2 bf2_to_f2(unsigned u) {
    return make_float2(__uint_as_float(u << 16),
                       __uint_as_float(u & 0xffff0000u));
}

// ===========================================================================
// FUSED cooperative kernel: phase A (normalize+pack) -> grid sync ->
// phase B (symmetric sim+exp+sums, persistent blocks) -> grid sync ->
// phase C (block 0: final loss reduction).
// Grid = 1024 blocks x 256 thr = exact co-residency at 4 blocks/CU.
// Fusing removes 2 kernel launches + 2 full pipeline drains vs the 3-kernel
// chain (the only part of the timed region we still control; round-1 showed
// the arithmetic itself is already far below the harness-reset floor).
// ===========================================================================
__global__ void __launch_bounds__(256, 4) fused_kernel(const float* __restrict__ f,
                                                       short* __restrict__ packed,
                                                       float* __restrict__ esum_g,
                                                       float* __restrict__ pos_g,
                                                       float* __restrict__ diag_g,
                                                       float* __restrict__ out) {
    const int tid  = threadIdx.x;
    const int w    = tid >> 6;
    const int lane = tid & 63;

    // ---------------- Phase A: L2-normalize rows, write fragment-packed bf16.
    // 4096 waves x 2 rows each = 8192 rows. Layout: frag (rb,ks) at flat
    // bf16x8 index (rb*4+ks)*64 + lane; lane = quad*16 + (r&15) holds
    // row r = rb*16+(lane&15), k = ks*32+quad*8..+8.
    {
        const int gw = blockIdx.x * 4 + w;       // 0..4095
        #pragma unroll
        for (int rep = 0; rep < 2; rep++) {
            const int row = gw * 2 + rep;
            const float2 v = ((const float2*)(f + (size_t)row * FDIM))[lane];
            float ss = v.x * v.x + v.y * v.y;
            #pragma unroll
            for (int m = 1; m < 64; m <<= 1) ss += __shfl_xor(ss, m);
            const float scale = 1.0f / fmaxf(sqrtf(ss), 1e-12f);

            const int off = ((((row >> 4) * 4 + (lane >> 4)) * 64)
                             + ((lane >> 2) & 3) * 16 + (row & 15)) * 8 + 2 * (lane & 3);
            __hip_bfloat16 b0 = __float2bfloat16(v.x * scale);
            __hip_bfloat16 b1 = __float2bfloat16(v.y * scale);
            unsigned u = (unsigned)*(unsigned short*)&b0
                       | ((unsigned)*(unsigned short*)&b1 << 16);
            *(unsigned*)(packed + off) = u;      // 4B-aligned (off is even)
        }
        if (blockIdx.x < 32) esum_g[blockIdx.x * 256 + tid] = 0.0f;
    }

    cg::grid_group grid = cg::this_grid();
    grid.sync();

    // ---------------- Phase B: symmetric sim+exp+sums over 1088 virtual
    // blocks (1056 upper-triangle tiles + 32 pos/diag), persistent loop.
    const int quad = lane >> 4;
    const int l16  = lane & 15;
    const bf16x8* P = (const bf16x8*)packed;
    __shared__ float colsum[256];

    for (int vb = blockIdx.x; vb < NBLK_ALL; vb += 1024) {
        if (vb >= NBLK_TRI) {
            // ---- pos/diag: one thread per row ----
            const int i  = (vb - NBLK_TRI) * 256 + tid;
            const int ip = i ^ HALF_N;
            const uint4* P4 = (const uint4*)packed;
            float dot = 0.f, self = 0.f;
            #pragma unroll
            for (int cc = 0; cc < 16; cc++) {    // cc = ks*4 + quad
                const uint4 a = P4[((i  >> 4) * 4 + (cc >> 2)) * 64 + (cc & 3) * 16 + (i  & 15)];
                const uint4 b = P4[((ip >> 4) * 4 + (cc >> 2)) * 64 + (cc & 3) * 16 + (ip & 15)];
                const unsigned au[4] = {a.x, a.y, a.z, a.w};
                const unsigned bu[4] = {b.x, b.y, b.z, b.w};
                #pragma unroll
                for (int q = 0; q < 4; q++) {
                    const float2 av = bf2_to_f2(au[q]);
                    const float2 bv = bf2_to_f2(bu[q]);
                    dot  = __builtin_fmaf(av.x, bv.x, __builtin_fmaf(av.y, bv.y, dot));
                    self = __builtin_fmaf(av.x, av.x, __builtin_fmaf(av.y, av.y, self));
                }
            }
            pos_g[i]  = dot;
            diag_g[i] = EXP2(__builtin_fmaf(self, K1, -K1));
            continue;
        }

        // ---- map tile id -> (J, rb), rb <= 2J+1; prefix(J) = J*(J+1) ----
        const int t = vb;
        int J = (int)((sqrtf(4.0f * (float)t + 1.0f) - 1.0f) * 0.5f);
        while ((J + 1) * (J + 2) <= t) J++;      // fixup float sqrt (scalar)
        while (J * (J + 1) > t) J--;
        const int rb = t - J * (J + 1);          // row block of 128 rows
        const bool upper = rb < 2 * J;           // strictly above the diagonal

        const int strip = rb * 4 + w;            // rows strip*32..+32
        colsum[tid] = 0.0f;

        // A fragments for this wave's 32 rows, parked: a_reg[ks][fr] (32 VGPR)
        bf16x8 a_reg[4][2];
        #pragma unroll
        for (int fr = 0; fr < 2; fr++)
            #pragma unroll
            for (int ks = 0; ks < 4; ks++)
                a_reg[ks][fr] = P[(((strip * 2 + fr) * 4) + ks) * 64 + lane];

        float ep[2][4];                          // [fr][r] row partials
        #pragma unroll
        for (int a = 0; a < 2; a++)
            #pragma unroll
            for (int b = 0; b < 4; b++) ep[a][b] = 0.0f;

        __syncthreads();                         // colsum init visible to all waves

        const int cb0 = J * 16;                  // 16 col-blocks of 16 cols

        #pragma unroll 8
        for (int cb = 0; cb < 16; cb++) {
            bf16x8 b[4];
            #pragma unroll
            for (int ks = 0; ks < 4; ks++)
                b[ks] = P[((cb0 + cb) * 4 + ks) * 64 + lane];

            f32x4 acc[2];
            #pragma unroll
            for (int fr = 0; fr < 2; fr++) acc[fr] = (f32x4){0.f, 0.f, 0.f, 0.f};
            #pragma unroll
            for (int ks = 0; ks < 4; ks++)
                #pragma unroll
                for (int fr = 0; fr < 2; fr++)
                    acc[fr] = __builtin_amdgcn_mfma_f32_16x16x32_bf16(
                                  a_reg[ks][fr], b[ks], acc[fr], 0, 0, 0);

            float cs = 0.0f;                     // this lane's col partial (8 rows)
            #pragma unroll
            for (int fr = 0; fr < 2; fr++)
                #pragma unroll
                for (int r = 0; r < 4; r++) {
                    const float e = EXP2(__builtin_fmaf(acc[fr][r], K1, -K1));
                    ep[fr][r] += e;
                    cs += e;
                }

            if (upper) {                         // wave-uniform branch
                cs += __shfl_xor(cs, 16);        // sum the 4 quads -> 32 rows
                cs += __shfl_xor(cs, 32);
                if (quad == 0)
                    atomicAdd(&colsum[cb * 16 + l16], cs);   // ds_add_f32
            }
        }

        // reduce row partials across the 16 column-lanes, commit per wave
        #pragma unroll
        for (int fr = 0; fr < 2; fr++)
            #pragma unroll
            for (int r = 0; r < 4; r++) {
                float v = ep[fr][r];
                #pragma unroll
                for (int m = 1; m < 16; m <<= 1) v += __shfl_xor(v, m);
                if (l16 == 0)
                    atomicAdd(&esum_g[strip * 32 + fr * 16 + quad * 4 + r], v);
            }

        // commit column sums (transpose contribution), coalesced atomics.
        // __syncthreads orders: commit-read of colsum[tid] (this iter) is
        // before the barrier; next iter's re-zero + LDS atomics are after
        // their own barrier -> no cross-iteration hazard.
        __syncthreads();
        if (upper) atomicAdd(&esum_g[J * 256 + tid], colsum[tid]);
    }

    grid.sync();

    // ---------------- Phase C: loss = mean_i[ ln(esum_i - diag_i) + 1/T - pos_i/T ]
    if (blockIdx.x == 0) {
        const float invT = 1.0f / 0.07f;
        float acc = 0.0f;
        for (int i = tid; i < NROWS; i += 256)
            acc += logf(esum_g[i] - diag_g[i]) + invT - pos_g[i] * invT;
        #pragma unroll
        for (int m = 1; m < 64; m <<= 1) acc += __shfl_xor(acc, m);
        __shared__ float ws[4];
        if ((tid & 63) == 0) ws[tid >> 6] = acc;
        __syncthreads();
        if (tid == 0) out[0] = (ws[0] + ws[1] + ws[2] + ws[3]) * (1.0f / (float)NROWS);
    }
}

// ===========================================================================
// Fallback 3-kernel path (used only if cooperative launch is rejected).
// ===========================================================================
__global__ void __launch_bounds__(256) normalize_kernel(const float* __restrict__ f,
                                                        short* __restrict__ packed,
                                                        float* __restrict__ esum_g) {
    const int row  = blockIdx.x * 4 + (threadIdx.x >> 6);
    const int lane = threadIdx.x & 63;
    const float2 v = ((const float2*)(f + (size_t)row * FDIM))[lane];
    float ss = v.x * v.x + v.y * v.y;
    #pragma unroll
    for (int m = 1; m < 64; m <<= 1) ss += __shfl_xor(ss, m);
    const float scale = 1.0f / fmaxf(sqrtf(ss), 1e-12f);

    const int off = ((((row >> 4) * 4 + (lane >> 4)) * 64)
                     + ((lane >> 2) & 3) * 16 + (row & 15)) * 8 + 2 * (lane & 3);
    __hip_bfloat16 b0 = __float2bfloat16(v.x * scale);
    __hip_bfloat16 b1 = __float2bfloat16(v.y * scale);
    unsigned u = (unsigned)*(unsigned short*)&b0
               | ((unsigned)*(unsigned short*)&b1 << 16);
    *(unsigned*)(packed + off) = u;

    if (threadIdx.x < 4) esum_g[blockIdx.x * 4 + threadIdx.x] = 0.0f;
}

__global__ void __launch_bounds__(256, 4) sim_kernel(const short* __restrict__ pk,
                                                     float* __restrict__ esum_g,
                                                     float* __restrict__ pos_g,
                                                     float* __restrict__ diag_g) {
    if (blockIdx.x >= NBLK_TRI) {
        const int i  = (blockIdx.x - NBLK_TRI) * 256 + threadIdx.x;
        const int ip = i ^ HALF_N;
        const uint4* P = (const uint4*)pk;
        float dot = 0.f, self = 0.f;
        #pragma unroll
        for (int cc = 0; cc < 16; cc++) {
            const uint4 a = P[((i  >> 4) * 4 + (cc >> 2)) * 64 + (cc & 3) * 16 + (i  & 15)];
            const uint4 b = P[((ip >> 4) * 4 + (cc >> 2)) * 64 + (cc & 3) * 16 + (ip & 15)];
            const unsigned au[4] = {a.x, a.y, a.z, a.w};
            const unsigned bu[4] = {b.x, b.y, b.z, b.w};
            #pragma unroll
            for (int q = 0; q < 4; q++) {
                const float2 av = bf2_to_f2(au[q]);
                const float2 bv = bf2_to_f2(bu[q]);
                dot  = __builtin_fmaf(av.x, bv.x, __builtin_fmaf(av.y, bv.y, dot));
                self = __builtin_fmaf(av.x, av.x, __builtin_fmaf(av.y, av.y, self));
            }
        }
        pos_g[i]  = dot;
        diag_g[i] = EXP2(__builtin_fmaf(self, K1, -K1));
        return;
    }

    const int t = blockIdx.x;
    int J = (int)((sqrtf(4.0f * (float)t + 1.0f) - 1.0f) * 0.5f);
    while ((J + 1) * (J + 2) <= t) J++;
    while (J * (J + 1) > t) J--;
    const int rb = t - J * (J + 1);
    const bool upper = rb < 2 * J;

    const int tid   = threadIdx.x;
    const int w     = tid >> 6;
    const int lane  = tid & 63;
    const int quad  = lane >> 4;
    const int l16   = lane & 15;
    const int strip = rb * 4 + w;
    const bf16x8* P = (const bf16x8*)pk;

    __shared__ float colsum[256];
    colsum[tid] = 0.0f;

    bf16x8 a_reg[4][2];
    #pragma unroll
    for (int fr = 0; fr < 2; fr++)
        #pragma unroll
        for (int ks = 0; ks < 4; ks++)
            a_reg[ks][fr] = P[(((strip * 2 + fr) * 4) + ks) * 64 + lane];

    float ep[2][4];
    #pragma unroll
    for (int a = 0; a < 2; a++)
        #pragma unroll
        for (int b = 0; b < 4; b++) ep[a][b] = 0.0f;

    __syncthreads();

    const int cb0 = J * 16;

    #pragma unroll 8
    for (int cb = 0; cb < 16; cb++) {
        bf16x8 b[4];
        #pragma unroll
        for (int ks = 0; ks < 4; ks++)
            b[ks] = P[((cb0 + cb) * 4 + ks) * 64 + lane];

        f32x4 acc[2];
        #pragma unroll
        for (int fr = 0; fr < 2; fr++) acc[fr] = (f32x4){0.f, 0.f, 0.f, 0.f};
        #pragma unroll
        for (int ks = 0; ks < 4; ks++)
            #pragma unroll
            for (int fr = 0; fr < 2; fr++)
                acc[fr] = __builtin_amdgcn_mfma_f32_16x16x32_bf16(
                              a_reg[ks][fr], b[ks], acc[fr], 0, 0, 0);

        float cs = 0.0f;
        #pragma unroll
        for (int fr = 0; fr < 2; fr++)
            #pragma unroll
            for (int r = 0; r < 4; r++) {
                const float e = EXP2(__builtin_fmaf(acc[fr][r], K1, -K1));
                ep[fr][r] += e;
                cs += e;
            }

        if (upper) {
            cs += __shfl_xor(cs, 16);
            cs += __shfl_xor(cs, 32);
            if (quad == 0)
                atomicAdd(&colsum[cb * 16 + l16], cs);
        }
    }

    #pragma unroll
    for (int fr = 0; fr < 2; fr++)
        #pragma unroll
        for (int r = 0; r < 4; r++) {
            float v = ep[fr][r];
            #pragma unroll
            for (int m = 1; m < 16; m <<= 1) v += __shfl_xor(v, m);
            if (l16 == 0)
                atomicAdd(&esum_g[strip * 32 + fr * 16 + quad * 4 + r], v);
        }

    __syncthreads();
    if (upper) atomicAdd(&esum_g[J * 256 + tid], colsum[tid]);
}

__global__ void __launch_bounds__(256) final_kernel(const float* __restrict__ esum_g,
                                                    const float* __restrict__ pos_g,
                                                    const float* __restrict__ diag_g,
                                                    float* __restrict__ out) {
    const int tid = threadIdx.x;
    const float invT = 1.0f / 0.07f;
    float acc = 0.0f;
    for (int i = tid; i < NROWS; i += 256)
        acc += logf(esum_g[i] - diag_g[i]) + invT - pos_g[i] * invT;
    #pragma unroll
    for (int m = 1; m < 64; m <<= 1) acc += __shfl_xor(acc, m);
    __shared__ float ws[4];
    if ((tid & 63) == 0) ws[tid >> 6] = acc;
    __syncthreads();
    if (tid == 0) out[0] = (ws[0] + ws[1] + ws[2] + ws[3]) * (1.0f / (float)NROWS);
}

// ---------------------------------------------------------------------------
extern "C" void kernel_launch(void* const* d_in, const int* in_sizes, int n_in,
                              void* d_out, int out_size, void* d_ws, size_t ws_size,
                              hipStream_t stream) {
    const float* features = (const float*)d_in[0];
    float* out = (float*)d_out;

    char* ws = (char*)d_ws;
    short* packed = (short*)ws;                                          // 2 MB
    float* esum_g = (float*)(ws + 2097152);                              // 32 KB
    float* pos_g  = (float*)(ws + 2097152 + 32768);                      // 32 KB
    float* diag_g = (float*)(ws + 2097152 + 65536);                      // 32 KB

    void* kargs[] = {(void*)&features, (void*)&packed, (void*)&esum_g,
                     (void*)&pos_g, (void*)&diag_g, (void*)&out};
    hipError_t err = hipLaunchCooperativeKernel((void*)fused_kernel,
                                                dim3(1024), dim3(256),
                                                kargs, 0, stream);
    if (err != hipSuccess) {
        // Fallback: 3-kernel chain (identical math).
        normalize_kernel<<<NROWS / 4, 256, 0, stream>>>(features, packed, esum_g);
        sim_kernel<<<NBLK_ALL, 256, 0, stream>>>(packed, esum_g, pos_g, diag_g);
        final_kernel<<<1, 256, 0, stream>>>(esum_g, pos_g, diag_g, out);
    }
}

// Round 3
// 92.949 us; speedup vs baseline: 3.7583x; 3.7583x over previous
//
#include <hip/hip_runtime.h>
#include <hip/hip_bf16.h>
#include <cstdint>

// Problem constants (reference: BATCH=4096, N_VIEWS=2, T=0.07, D=128 -> N=8192)
#define NROWS 8192
#define FDIM  128
#define HALF_N 4096

typedef short bf16x8 __attribute__((ext_vector_type(8)));   // 8 bf16 = 4 VGPRs
typedef float f32x4  __attribute__((ext_vector_type(4)));

// k1 = log2(e)/T so exp((s-1)/T) = exp2(k1*s - k1)
#define K1 (1.4426950408889634f / 0.07f)

#if __has_builtin(__builtin_amdgcn_exp2f)
#define EXP2(x) __builtin_amdgcn_exp2f(x)       // raw v_exp_f32
#else
#define EXP2(x) exp2f(x)
#endif

// Upper-triangle block count at (128-row x 256-col) granularity:
// per col-group J (0..31), rb = 0..2J+1 kept -> sum(2J+2) = 32*33 = 1056.
#define NBLK_TRI 1056
#define NBLK_ALL (NBLK_TRI + 32)     // + pos/diag blocks

// Fragment-packed layout of the normalized bf16 matrix:
//   frag (rb, ks) at flat bf16x8 index (rb*4+ks)*64 + lane,
//   lane = quad*16 + (r&15) holds row r = rb*16+(lane&15), k = ks*32+quad*8..+8.
// One coalesced global_load_dwordx4 per fragment. 2 MB total.
//
// NOTE (round-2 lesson): a fused cooperative-kernel version of this chain ran
// 292 us — grid.sync() across 8 non-coherent-XCD L2s costs ~140 us each.
// Stream-ordered launches are the cheap barrier on MI355X. Keep 3 kernels.

// ---------------------------------------------------------------------------
// Kernel 1: L2-normalize rows (fp32, matching ref), write fragment-packed
// bf16. Also zero-inits esum_g.
// ---------------------------------------------------------------------------
__global__ void __launch_bounds__(256) normalize_kernel(const float* __restrict__ f,
                                                        short* __restrict__ packed,
                                                        float* __restrict__ esum_g) {
    const int row  = blockIdx.x * 4 + (threadIdx.x >> 6);
    const int lane = threadIdx.x & 63;           // element k = 2*lane, 2*lane+1
    const float2 v = ((const float2*)(f + (size_t)row * FDIM))[lane];
    float ss = v.x * v.x + v.y * v.y;
    #pragma unroll
    for (int m = 1; m < 64; m <<= 1) ss += __shfl_xor(ss, m);
    const float scale = 1.0f / fmaxf(sqrtf(ss), 1e-12f);

    const int off = ((((row >> 4) * 4 + (lane >> 4)) * 64)
                     + ((lane >> 2) & 3) * 16 + (row & 15)) * 8 + 2 * (lane & 3);
    __hip_bfloat16 b0 = __float2bfloat16(v.x * scale);
    __hip_bfloat16 b1 = __float2bfloat16(v.y * scale);
    unsigned u = (unsigned)*(unsigned short*)&b0
               | ((unsigned)*(unsigned short*)&b1 << 16);
    *(unsigned*)(packed + off) = u;              // 4B-aligned (off is even)

    if (threadIdx.x < 4) esum_g[blockIdx.x * 4 + threadIdx.x] = 0.0f;
}

__device__ __forceinline__ float2 bf2_to_f2(unsigned u) {
    return make_float2(__uint_as_float(u << 16),
                       __uint_as_float(u & 0xffff0000u));
}

// ---------------------------------------------------------------------------
// Kernel 2: SYMMETRIC sim+exp+rowsum. sim = F F^T is symmetric, so only the
// upper triangle of (128-row x 256-col) tiles is computed: block t -> (J, rb)
// with rb <= 2J+1 (1056 blocks).
//   - rb in {2J, 2J+1}: "diagonal" blocks — rows lie inside the col range;
//     the two of them cover the 256x256 diagonal super-tile fully; ROW sums
//     only (i==i term subtracted via diag_g in the final kernel).
//   - rb < 2J: strictly-upper blocks. Each e = exp((s_rc-1)/T) feeds BOTH
//     esum[r] (row partials in registers) and esum[c] (per-lane sum of its
//     8 e's -> shfl_xor across quads -> LDS colsum -> one coalesced
//     global-atomic commit per block).
// Grid 1088 blocks (~4.25/CU) at __launch_bounds__(256,4): 4 waves/SIMD.
// Blocks 1056..1087: pos_i = <f_i, f_(i^4096)>, diag_i = exp((<f_i,f_i>-1)/T).
// ---------------------------------------------------------------------------
__global__ void __launch_bounds__(256, 4) sim_kernel(const short* __restrict__ pk,
                                                     float* __restrict__ esum_g,
                                                     float* __restrict__ pos_g,
                                                     float* __restrict__ diag_g) {
    if (blockIdx.x >= NBLK_TRI) {
        // ---- pos/diag path: one thread per row ----
        const int i  = (blockIdx.x - NBLK_TRI) * 256 + threadIdx.x;
        const int ip = i ^ HALF_N;
        const uint4* P = (const uint4*)pk;
        float dot = 0.f, self = 0.f;
        #pragma unroll
        for (int cc = 0; cc < 16; cc++) {        // cc = ks*4 + quad
            const uint4 a = P[((i  >> 4) * 4 + (cc >> 2)) * 64 + (cc & 3) * 16 + (i  & 15)];
            const uint4 b = P[((ip >> 4) * 4 + (cc >> 2)) * 64 + (cc & 3) * 16 + (ip & 15)];
            const unsigned au[4] = {a.x, a.y, a.z, a.w};
            const unsigned bu[4] = {b.x, b.y, b.z, b.w};
            #pragma unroll
            for (int q = 0; q < 4; q++) {
                const float2 av = bf2_to_f2(au[q]);
                const float2 bv = bf2_to_f2(bu[q]);
                dot  = __builtin_fmaf(av.x, bv.x, __builtin_fmaf(av.y, bv.y, dot));
                self = __builtin_fmaf(av.x, av.x, __builtin_fmaf(av.y, av.y, self));
            }
        }
        pos_g[i]  = dot;
        diag_g[i] = EXP2(__builtin_fmaf(self, K1, -K1));
        return;
    }

    // ---- map block id -> (J, rb), rb <= 2J+1; prefix(J) = J*(J+1) ----
    const int t = blockIdx.x;
    int J = (int)((sqrtf(4.0f * (float)t + 1.0f) - 1.0f) * 0.5f);
    while ((J + 1) * (J + 2) <= t) J++;          // fixup float sqrt (scalar)
    while (J * (J + 1) > t) J--;
    const int rb = t - J * (J + 1);              // row block of 128 rows
    const bool upper = rb < 2 * J;               // strictly above the diagonal

    const int tid   = threadIdx.x;
    const int w     = tid >> 6;
    const int lane  = tid & 63;
    const int quad  = lane >> 4;
    const int l16   = lane & 15;
    const int strip = rb * 4 + w;                // 0..255: rows strip*32..+32
    const bf16x8* P = (const bf16x8*)pk;

    __shared__ float colsum[256];
    colsum[tid] = 0.0f;

    // A fragments for this wave's 32 rows, parked: a_reg[ks][fr] (32 VGPR)
    bf16x8 a_reg[4][2];
    #pragma unroll
    for (int fr = 0; fr < 2; fr++)
        #pragma unroll
        for (int ks = 0; ks < 4; ks++)
            a_reg[ks][fr] = P[(((strip * 2 + fr) * 4) + ks) * 64 + lane];

    float ep[2][4];                              // [fr][r] row partials
    #pragma unroll
    for (int a = 0; a < 2; a++)
        #pragma unroll
        for (int b = 0; b < 4; b++) ep[a][b] = 0.0f;

    __syncthreads();                             // colsum init visible to all waves

    const int cb0 = J * 16;                      // 16 col-blocks of 16 cols

    #pragma unroll 8
    for (int cb = 0; cb < 16; cb++) {
        bf16x8 b[4];
        #pragma unroll
        for (int ks = 0; ks < 4; ks++)
            b[ks] = P[((cb0 + cb) * 4 + ks) * 64 + lane];

        f32x4 acc[2];
        #pragma unroll
        for (int fr = 0; fr < 2; fr++) acc[fr] = (f32x4){0.f, 0.f, 0.f, 0.f};
        #pragma unroll
        for (int ks = 0; ks < 4; ks++)
            #pragma unroll
            for (int fr = 0; fr < 2; fr++)
                acc[fr] = __builtin_amdgcn_mfma_f32_16x16x32_bf16(
                              a_reg[ks][fr], b[ks], acc[fr], 0, 0, 0);

        float cs = 0.0f;                         // this lane's col partial (8 rows)
        #pragma unroll
        for (int fr = 0; fr < 2; fr++)
            #pragma unroll
            for (int r = 0; r < 4; r++) {
                const float e = EXP2(__builtin_fmaf(acc[fr][r], K1, -K1));
                ep[fr][r] += e;
                cs += e;
            }

        if (upper) {                             // wave-uniform branch
            cs += __shfl_xor(cs, 16);            // sum the 4 quads -> 32 rows
            cs += __shfl_xor(cs, 32);
            if (quad == 0)
                atomicAdd(&colsum[cb * 16 + l16], cs);   // ds_add_f32, races ok
        }
    }

    // reduce row partials across the 16 column-lanes, commit once per wave
    #pragma unroll
    for (int fr = 0; fr < 2; fr++)
        #pragma unroll
        for (int r = 0; r < 4; r++) {
            float v = ep[fr][r];
            #pragma unroll
            for (int m = 1; m < 16; m <<= 1) v += __shfl_xor(v, m);
            if (l16 == 0)
                atomicAdd(&esum_g[strip * 32 + fr * 16 + quad * 4 + r], v);
        }

    // commit column sums (transpose contribution), one coalesced atomic/thread
    __syncthreads();
    if (upper) atomicAdd(&esum_g[J * 256 + tid], colsum[tid]);
}

// ---------------------------------------------------------------------------
// Kernel 3: loss_i = ln(esum_i - diag_i) + 1/T - pos_i/T ; out = mean(loss).
// ---------------------------------------------------------------------------
__global__ void __launch_bounds__(256) final_kernel(const float* __restrict__ esum_g,
                                                    const float* __restrict__ pos_g,
                                                    const float* __restrict__ diag_g,
                                                    float* __restrict__ out) {
    const int tid = threadIdx.x;
    const float invT = 1.0f / 0.07f;
    float acc = 0.0f;
    for (int i = tid; i < NROWS; i += 256)
        acc += logf(esum_g[i] - diag_g[i]) + invT - pos_g[i] * invT;
    #pragma unroll
    for (int m = 1; m < 64; m <<= 1) acc += __shfl_xor(acc, m);
    __shared__ float ws[4];
    if ((tid & 63) == 0) ws[tid >> 6] = acc;
    __syncthreads();
    if (tid == 0) out[0] = (ws[0] + ws[1] + ws[2] + ws[3]) * (1.0f / (float)NROWS);
}

// ---------------------------------------------------------------------------
extern "C" void kernel_launch(void* const* d_in, const int* in_sizes, int n_in,
                              void* d_out, int out_size, void* d_ws, size_t ws_size,
                              hipStream_t stream) {
    const float* features = (const float*)d_in[0];
    float* out = (float*)d_out;

    char* ws = (char*)d_ws;
    short* packed = (short*)ws;                                          // 2 MB
    float* esum_g = (float*)(ws + 2097152);                              // 32 KB
    float* pos_g  = (float*)(ws + 2097152 + 32768);                      // 32 KB
    float* diag_g = (float*)(ws + 2097152 + 65536);                      // 32 KB

    normalize_kernel<<<NROWS / 4, 256, 0, stream>>>(features, packed, esum_g);

    sim_kernel<<<NBLK_ALL, 256, 0, stream>>>(packed, esum_g, pos_g, diag_g);

    final_kernel<<<1, 256, 0, stream>>>(esum_g, pos_g, diag_g, out);
}

// Round 4
// 89.234 us; speedup vs baseline: 3.9148x; 1.0416x over previous
//
#include <hip/hip_runtime.h>
#include <hip/hip_bf16.h>
#include <cstdint>

// Problem constants (reference: BATCH=4096, N_VIEWS=2, T=0.07, D=128 -> N=8192)
#define NROWS 8192
#define FDIM  128
#define HALF_N 4096

typedef short bf16x8 __attribute__((ext_vector_type(8)));   // 8 bf16 = 4 VGPRs
typedef float f32x4  __attribute__((ext_vector_type(4)));

// k1 = log2(e)/T so exp((s-1)/T) = exp2(k1*s - k1)
#define K1 (1.4426950408889634f / 0.07f)

#if __has_builtin(__builtin_amdgcn_exp2f)
#define EXP2(x) __builtin_amdgcn_exp2f(x)       // raw v_exp_f32
#else
#define EXP2(x) exp2f(x)
#endif

// Fragment-packed layout of the normalized bf16 matrix:
//   frag (rb, ks) at flat bf16x8 index (rb*4+ks)*64 + lane,
//   lane = quad*16 + (r&15) holds row r = rb*16+(lane&15), k = ks*32+quad*8..+8.
// One coalesced global_load_dwordx4 per fragment. 2 MB total.
//
// Session notes (rounds 0-3):
//  - Timed region is dominated by the harness's 256 MiB workspace re-poison
//    fills (~41 us each at ~81% of achievable HBM BW); our whole 3-kernel
//    chain is < 10 us and below round-to-round fill noise.
//  - Symmetric (upper-triangle) sim with column-sum atomics: half the FLOPs
//    but +3 us end-to-end — device-scope atomic contention on the column
//    commits (up to 62 blocks adding into the same 256 words) lands in the
//    kernel tail. Arithmetic was never the constraint. Reverted.
//  - Cooperative-kernel fusion of the 3 phases: 292 us. grid.sync() across
//    8 non-coherent-XCD L2s costs ~140 us each. Never grid-sync short phases
//    on MI355X; stream-ordered launches are the cheap barrier.

// ---------------------------------------------------------------------------
// Kernel 1: L2-normalize rows (fp32, matching ref), write fragment-packed
// bf16. Also zero-inits esum_g.
// ---------------------------------------------------------------------------
__global__ void __launch_bounds__(256) normalize_kernel(const float* __restrict__ f,
                                                        short* __restrict__ packed,
                                                        float* __restrict__ esum_g) {
    const int row  = blockIdx.x * 4 + (threadIdx.x >> 6);
    const int lane = threadIdx.x & 63;           // element k = 2*lane, 2*lane+1
    const float2 v = ((const float2*)(f + (size_t)row * FDIM))[lane];
    float ss = v.x * v.x + v.y * v.y;
    #pragma unroll
    for (int m = 1; m < 64; m <<= 1) ss += __shfl_xor(ss, m);
    const float scale = 1.0f / fmaxf(sqrtf(ss), 1e-12f);

    const int off = ((((row >> 4) * 4 + (lane >> 4)) * 64)
                     + ((lane >> 2) & 3) * 16 + (row & 15)) * 8 + 2 * (lane & 3);
    __hip_bfloat16 b0 = __float2bfloat16(v.x * scale);
    __hip_bfloat16 b1 = __float2bfloat16(v.y * scale);
    unsigned u = (unsigned)*(unsigned short*)&b0
               | ((unsigned)*(unsigned short*)&b1 << 16);
    *(unsigned*)(packed + off) = u;              // 4B-aligned (off is even)

    if (threadIdx.x < 4) esum_g[blockIdx.x * 4 + threadIdx.x] = 0.0f;
}

__device__ __forceinline__ float2 bf2_to_f2(unsigned u) {
    return make_float2(__uint_as_float(u << 16),
                       __uint_as_float(u & 0xffff0000u));
}

// ---------------------------------------------------------------------------
// Kernel 2: full-matrix fused sim+exp+rowsum.
// 4096 compute waves: wave = (strip of 32 rows, j of 512 cols). Block = 4
// waves sharing j over strips sg*4..+3 (B-stream aliases in L1; A contiguous).
// Grid 1024 -> 4 blocks/CU, __launch_bounds__(256,4): 4 waves/SIMD of latency
// hiding. A parked in 32 VGPR; per cb (16 cols): 4 B-frag loads + 8 MFMA +
// 8 exp2 per lane; unroll-8 lets the compiler hoist loads across iterations.
// esum includes the diagonal term (subtracted in final via diag_g).
// Blocks 1024..1055: pos_i = <f_i, f_(i^4096)>, diag_i = exp((<f_i,f_i>-1)/T).
// ---------------------------------------------------------------------------
__global__ void __launch_bounds__(256, 4) sim_kernel(const short* __restrict__ pk,
                                                     float* __restrict__ esum_g,
                                                     float* __restrict__ pos_g,
                                                     float* __restrict__ diag_g) {
    if (blockIdx.x >= 1024) {
        // ---- pos/diag path: one thread per row ----
        const int i  = (blockIdx.x - 1024) * 256 + threadIdx.x;
        const int ip = i ^ HALF_N;
        const uint4* P = (const uint4*)pk;
        float dot = 0.f, self = 0.f;
        #pragma unroll
        for (int cc = 0; cc < 16; cc++) {        // cc = ks*4 + quad
            const uint4 a = P[((i  >> 4) * 4 + (cc >> 2)) * 64 + (cc & 3) * 16 + (i  & 15)];
            const uint4 b = P[((ip >> 4) * 4 + (cc >> 2)) * 64 + (cc & 3) * 16 + (ip & 15)];
            const unsigned au[4] = {a.x, a.y, a.z, a.w};
            const unsigned bu[4] = {b.x, b.y, b.z, b.w};
            #pragma unroll
            for (int q = 0; q < 4; q++) {
                const float2 av = bf2_to_f2(au[q]);
                const float2 bv = bf2_to_f2(bu[q]);
                dot  = __builtin_fmaf(av.x, bv.x, __builtin_fmaf(av.y, bv.y, dot));
                self = __builtin_fmaf(av.x, av.x, __builtin_fmaf(av.y, av.y, self));
            }
        }
        pos_g[i]  = dot;
        diag_g[i] = EXP2(__builtin_fmaf(self, K1, -K1));
        return;
    }

    const int tid   = threadIdx.x;
    const int w     = tid >> 6;
    const int lane  = tid & 63;
    const int quad  = lane >> 4;
    const int l16   = lane & 15;
    const int j     = blockIdx.x & 15;           // col group (512 cols), SHARED
    const int strip = (blockIdx.x >> 4) * 4 + w; // 0..255: rows strip*32..+32
    const bf16x8* P = (const bf16x8*)pk;

    // A fragments for this wave's 32 rows, parked: a_reg[ks][fr] (32 VGPR)
    bf16x8 a_reg[4][2];
    #pragma unroll
    for (int fr = 0; fr < 2; fr++)
        #pragma unroll
        for (int ks = 0; ks < 4; ks++)
            a_reg[ks][fr] = P[(((strip * 2 + fr) * 4) + ks) * 64 + lane];

    float ep[2][4];                              // [fr][r] row partials
    #pragma unroll
    for (int a = 0; a < 2; a++)
        #pragma unroll
        for (int b = 0; b < 4; b++) ep[a][b] = 0.0f;

    const int cb0 = j * 32;                      // 32 col-blocks of 16

    #pragma unroll 8
    for (int cb = 0; cb < 32; cb++) {
        bf16x8 b[4];
        #pragma unroll
        for (int ks = 0; ks < 4; ks++)
            b[ks] = P[((cb0 + cb) * 4 + ks) * 64 + lane];

        f32x4 acc[2];
        #pragma unroll
        for (int fr = 0; fr < 2; fr++) acc[fr] = (f32x4){0.f, 0.f, 0.f, 0.f};
        #pragma unroll
        for (int ks = 0; ks < 4; ks++)
            #pragma unroll
            for (int fr = 0; fr < 2; fr++)
                acc[fr] = __builtin_amdgcn_mfma_f32_16x16x32_bf16(
                              a_reg[ks][fr], b[ks], acc[fr], 0, 0, 0);

        #pragma unroll
        for (int fr = 0; fr < 2; fr++)
            #pragma unroll
            for (int r = 0; r < 4; r++)
                ep[fr][r] += EXP2(__builtin_fmaf(acc[fr][r], K1, -K1));
    }

    // reduce row partials across the 16 column-lanes, commit once per wave
    #pragma unroll
    for (int fr = 0; fr < 2; fr++)
        #pragma unroll
        for (int r = 0; r < 4; r++) {
            float v = ep[fr][r];
            #pragma unroll
            for (int m = 1; m < 16; m <<= 1) v += __shfl_xor(v, m);
            if (l16 == 0)
                atomicAdd(&esum_g[strip * 32 + fr * 16 + quad * 4 + r], v);
        }
}

// ---------------------------------------------------------------------------
// Kernel 3: loss_i = ln(esum_i - diag_i) + 1/T - pos_i/T ; out = mean(loss).
// ---------------------------------------------------------------------------
__global__ void __launch_bounds__(256) final_kernel(const float* __restrict__ esum_g,
                                                    const float* __restrict__ pos_g,
                                                    const float* __restrict__ diag_g,
                                                    float* __restrict__ out) {
    const int tid = threadIdx.x;
    const float invT = 1.0f / 0.07f;
    float acc = 0.0f;
    for (int i = tid; i < NROWS; i += 256)
        acc += logf(esum_g[i] - diag_g[i]) + invT - pos_g[i] * invT;
    #pragma unroll
    for (int m = 1; m < 64; m <<= 1) acc += __shfl_xor(acc, m);
    __shared__ float ws[4];
    if ((tid & 63) == 0) ws[tid >> 6] = acc;
    __syncthreads();
    if (tid == 0) out[0] = (ws[0] + ws[1] + ws[2] + ws[3]) * (1.0f / (float)NROWS);
}

// ---------------------------------------------------------------------------
extern "C" void kernel_launch(void* const* d_in, const int* in_sizes, int n_in,
                              void* d_out, int out_size, void* d_ws, size_t ws_size,
                              hipStream_t stream) {
    const float* features = (const float*)d_in[0];
    float* out = (float*)d_out;

    char* ws = (char*)d_ws;
    short* packed = (short*)ws;                                          // 2 MB
    float* esum_g = (float*)(ws + 2097152);                              // 32 KB
    float* pos_g  = (float*)(ws + 2097152 + 32768);                      // 32 KB
    float* diag_g = (float*)(ws + 2097152 + 65536);                      // 32 KB

    normalize_kernel<<<NROWS / 4, 256, 0, stream>>>(features, packed, esum_g);

    sim_kernel<<<1024 + NROWS / 256, 256, 0, stream>>>(packed, esum_g, pos_g, diag_g);

    final_kernel<<<1, 256, 0, stream>>>(esum_g, pos_g, diag_g, out);
}